// Round 2
// baseline (6318.217 us; speedup 1.0000x reference)
//
#include <hip/hip_runtime.h>

// Problem constants (from setup_inputs: B=8, C=3, H=W=1024, all float32)
constexpr int B_ = 8;
constexpr int C_ = 3;
constexpr int H_ = 1024;
constexpr int W_ = 1024;
constexpr int HW_ = H_ * W_;

// ---------------------------------------------------------------------------
// Packed path: acc is [B][HW][4] floats (R,G,B,normweight interleaved) so the
// 4 atomics per splat corner hit one 16B span (one cache line) instead of 4
// lines in 4 separate planes.
// XCD swizzle: grid = B*HW/256 = 32768 blocks; hardware round-robins blocks
// across 8 XCDs, so batch = blockIdx.x & 7 pins each batch's accumulator
// traffic to a single XCD's L2 (live window ~40 rows ≈ 640 KB < 4 MB).
// ---------------------------------------------------------------------------
__global__ __launch_bounds__(256) void splat_packed_kernel(
    const float* __restrict__ img,
    const float* __restrict__ flow,
    const float* __restrict__ metric,
    float* __restrict__ acc)
{
    const int b = blockIdx.x & 7;                       // batch == XCD
    const int p = ((blockIdx.x >> 3) << 8) + threadIdx.x;  // pixel in batch
    const int y = p >> 10;
    const int x = p & (W_ - 1);

    const float fx = flow[(size_t)(b * 2 + 0) * HW_ + p] + (float)x;
    const float fy = flow[(size_t)(b * 2 + 1) * HW_ + p] + (float)y;
    const float wgt = __expf(metric[(size_t)b * HW_ + p]);

    const float v0 = img[(size_t)(b * 3 + 0) * HW_ + p] * wgt;
    const float v1 = img[(size_t)(b * 3 + 1) * HW_ + p] * wgt;
    const float v2 = img[(size_t)(b * 3 + 2) * HW_ + p] * wgt;

    const float x0f = floorf(fx);
    const float y0f = floorf(fy);
    const int x0 = (int)x0f;
    const int y0 = (int)y0f;
    const float wx1 = fx - x0f;
    const float wx0 = 1.0f - wx1;
    const float wy1 = fy - y0f;
    const float wy0 = 1.0f - wy1;

    float* const accb = acc + (size_t)b * HW_ * 4;

#pragma unroll
    for (int dy = 0; dy < 2; ++dy) {
        const int yi = y0 + dy;
        if (yi < 0 || yi >= H_) continue;
        const float wy = dy ? wy1 : wy0;
#pragma unroll
        for (int dx = 0; dx < 2; ++dx) {
            const int xi = x0 + dx;
            if (xi < 0 || xi >= W_) continue;
            const float w = (dx ? wx1 : wx0) * wy;
            float* const dst = accb + (size_t)(yi * W_ + xi) * 4;
            unsafeAtomicAdd(dst + 0, v0 * w);
            unsafeAtomicAdd(dst + 1, v1 * w);
            unsafeAtomicAdd(dst + 2, v2 * w);
            unsafeAtomicAdd(dst + 3, wgt * w);
        }
    }
}

__global__ __launch_bounds__(256) void normalize_packed_kernel(
    const float4* __restrict__ acc,
    float* __restrict__ out)
{
    const int t = blockIdx.x * 256 + threadIdx.x;   // one thread per pixel
    if (t >= B_ * HW_) return;
    const int b = t >> 20;
    const int p = t & (HW_ - 1);

    const float4 a = acc[t];
    const float inv = (a.w == 0.0f) ? 1.0f : 1.0f / a.w;
    out[(size_t)(b * 3 + 0) * HW_ + p] = a.x * inv;
    out[(size_t)(b * 3 + 1) * HW_ + p] = a.y * inv;
    out[(size_t)(b * 3 + 2) * HW_ + p] = a.z * inv;
}

// ---------------------------------------------------------------------------
// Fallback (ws too small for packed acc): round-1 planar scheme.
// ---------------------------------------------------------------------------
__global__ __launch_bounds__(256) void splat_planar_kernel(
    const float* __restrict__ img,
    const float* __restrict__ flow,
    const float* __restrict__ metric,
    float* __restrict__ out,
    float* __restrict__ norm)
{
    const int t = blockIdx.x * blockDim.x + threadIdx.x;
    if (t >= B_ * HW_) return;
    const int b = t >> 20;
    const int p = t & (HW_ - 1);
    const int y = p >> 10;
    const int x = p & (W_ - 1);

    const float fx = flow[(size_t)(b * 2 + 0) * HW_ + p] + (float)x;
    const float fy = flow[(size_t)(b * 2 + 1) * HW_ + p] + (float)y;
    const float wgt = __expf(metric[(size_t)b * HW_ + p]);

    const float v0 = img[(size_t)(b * 3 + 0) * HW_ + p] * wgt;
    const float v1 = img[(size_t)(b * 3 + 1) * HW_ + p] * wgt;
    const float v2 = img[(size_t)(b * 3 + 2) * HW_ + p] * wgt;

    const float x0f = floorf(fx);
    const float y0f = floorf(fy);
    const int x0 = (int)x0f;
    const int y0 = (int)y0f;
    const float wx1 = fx - x0f;
    const float wx0 = 1.0f - wx1;
    const float wy1 = fy - y0f;
    const float wy0 = 1.0f - wy1;

    float* const outb = out + (size_t)b * 3 * HW_;
    float* const normb = norm + (size_t)b * HW_;

#pragma unroll
    for (int dy = 0; dy < 2; ++dy) {
        const int yi = y0 + dy;
        if (yi < 0 || yi >= H_) continue;
        const float wy = dy ? wy1 : wy0;
#pragma unroll
        for (int dx = 0; dx < 2; ++dx) {
            const int xi = x0 + dx;
            if (xi < 0 || xi >= W_) continue;
            const float w = (dx ? wx1 : wx0) * wy;
            const int q = yi * W_ + xi;
            unsafeAtomicAdd(outb + q,           v0 * w);
            unsafeAtomicAdd(outb + HW_ + q,     v1 * w);
            unsafeAtomicAdd(outb + 2 * HW_ + q, v2 * w);
            unsafeAtomicAdd(normb + q,          wgt * w);
        }
    }
}

__global__ __launch_bounds__(256) void normalize_planar_kernel(
    float* __restrict__ out,
    const float* __restrict__ norm)
{
    const int t = blockIdx.x * blockDim.x + threadIdx.x;
    constexpr int Q = HW_ / 4;
    if (t >= B_ * Q) return;
    const int b = t / Q;
    const int p4 = t - b * Q;

    const float4 n4 = reinterpret_cast<const float4*>(norm + (size_t)b * HW_)[p4];
    const float ix = (n4.x == 0.0f) ? 1.0f : 1.0f / n4.x;
    const float iy = (n4.y == 0.0f) ? 1.0f : 1.0f / n4.y;
    const float iz = (n4.z == 0.0f) ? 1.0f : 1.0f / n4.z;
    const float iw = (n4.w == 0.0f) ? 1.0f : 1.0f / n4.w;

#pragma unroll
    for (int c = 0; c < 3; ++c) {
        float4* plane = reinterpret_cast<float4*>(out + (size_t)(b * 3 + c) * HW_);
        float4 v = plane[p4];
        v.x *= ix; v.y *= iy; v.z *= iz; v.w *= iw;
        plane[p4] = v;
    }
}

extern "C" void kernel_launch(void* const* d_in, const int* in_sizes, int n_in,
                              void* d_out, int out_size, void* d_ws, size_t ws_size,
                              hipStream_t stream)
{
    const float* img    = (const float*)d_in[0];
    const float* flow   = (const float*)d_in[1];
    const float* metric = (const float*)d_in[2];
    float* out = (float*)d_out;

    const size_t packed_bytes = (size_t)B_ * HW_ * 4 * sizeof(float);  // 128 MB

    if (ws_size >= packed_bytes) {
        float* acc = (float*)d_ws;
        hipMemsetAsync(acc, 0, packed_bytes, stream);

        const int blocks = B_ * HW_ / 256;   // 32768
        splat_packed_kernel<<<blocks, 256, 0, stream>>>(img, flow, metric, acc);

        const int nblocks = (B_ * HW_ + 255) / 256;
        normalize_packed_kernel<<<nblocks, 256, 0, stream>>>(
            (const float4*)acc, out);
    } else {
        float* norm = (float*)d_ws;  // B*HW floats = 32 MB
        hipMemsetAsync(out,  0, (size_t)B_ * 3 * HW_ * sizeof(float), stream);
        hipMemsetAsync(norm, 0, (size_t)B_ * HW_ * sizeof(float), stream);

        const int n = B_ * HW_;
        const int blocks = (n + 255) / 256;
        splat_planar_kernel<<<blocks, 256, 0, stream>>>(img, flow, metric, out, norm);

        const int n4 = B_ * (HW_ / 4);
        normalize_planar_kernel<<<(n4 + 255) / 256, 256, 0, stream>>>(out, norm);
    }
}

// Round 3
// 710.730 us; speedup vs baseline: 8.8898x; 8.8898x over previous
//
#include <hip/hip_runtime.h>

// Problem constants (from setup_inputs: B=8, C=3, H=W=1024, all float32)
constexpr int B_ = 8;
constexpr int H_ = 1024;
constexpr int W_ = 1024;
constexpr int HW_ = H_ * W_;

// Tile geometry. R bounds the splat reach handled by the tile pass; flow is
// N(0,4) so P(|flow|>24) ~ 2e-9/pixel — the outlier list handles the rest
// exactly.
constexpr int TW = 64;
constexpr int TH = 64;
constexpr int R  = 24;
constexpr int WX = TW + 2 * R;   // 112 source window width
constexpr int WY = TH + 2 * R;   // 112 source window height
constexpr int NT = 512;          // threads per tile block
constexpr int LSTRIDE = TW + 1;  // LDS row pad: +1 breaks same-bank rows

// ---------------------------------------------------------------------------
// Outlier pass: pixels whose splat reaches beyond R from the source are
// appended to a global record list (bump allocator). Expected count ~0.
// ---------------------------------------------------------------------------
__global__ __launch_bounds__(256) void outlier_kernel(
    const float* __restrict__ img,
    const float* __restrict__ flow,
    const float* __restrict__ metric,
    int* __restrict__ counter,
    float4* __restrict__ rec_vals,
    int* __restrict__ rec_cells,
    int cap)
{
    const int t = blockIdx.x * 256 + threadIdx.x;
    if (t >= B_ * HW_) return;
    const int b = t >> 20;
    const int p = t & (HW_ - 1);
    const int y = p >> 10;
    const int x = p & (W_ - 1);

    const float fx = flow[(size_t)(b * 2 + 0) * HW_ + p] + (float)x;
    const float fy = flow[(size_t)(b * 2 + 1) * HW_ + p] + (float)y;
    const float x0f = floorf(fx);
    const float y0f = floorf(fy);
    const int x0 = (int)x0f;
    const int y0 = (int)y0f;

    // Fast reject: all 4 corners within R of source? (the overwhelmingly
    // common case — whole wave exits here)
    const bool far = (abs(x0 - x) > R) || (abs(x0 + 1 - x) > R) ||
                     (abs(y0 - y) > R) || (abs(y0 + 1 - y) > R);
    if (!far) return;

    const float wgt = __expf(metric[(size_t)b * HW_ + p]);
    const float v0 = img[(size_t)(b * 3 + 0) * HW_ + p] * wgt;
    const float v1 = img[(size_t)(b * 3 + 1) * HW_ + p] * wgt;
    const float v2 = img[(size_t)(b * 3 + 2) * HW_ + p] * wgt;
    const float wx1 = fx - x0f, wx0 = 1.0f - wx1;
    const float wy1 = fy - y0f, wy0 = 1.0f - wy1;

#pragma unroll
    for (int dy = 0; dy < 2; ++dy) {
        const int yi = y0 + dy;
        if (yi < 0 || yi >= H_) continue;
#pragma unroll
        for (int dx = 0; dx < 2; ++dx) {
            const int xi = x0 + dx;
            if (xi < 0 || xi >= W_) continue;
            // corner handled by the tile pass iff within R in both axes
            if (abs(xi - x) <= R && abs(yi - y) <= R) continue;
            const float w = (dx ? wx1 : wx0) * (dy ? wy1 : wy0);
            const int idx = atomicAdd(counter, 1);
            if (idx < cap) {
                rec_cells[idx] = (b << 20) | (yi << 10) | xi;
                rec_vals[idx]  = make_float4(v0 * w, v1 * w, v2 * w, wgt * w);
            }
        }
    }
}

// ---------------------------------------------------------------------------
// Tile pass: each block owns one 64x64 output tile, accumulates all local
// splat contributions in LDS (ds_add_f32 atomics), folds in outlier records,
// normalizes, and writes the 3 output planes with plain stores.
// ---------------------------------------------------------------------------
__global__ __launch_bounds__(NT) void splat_tile_kernel(
    const float* __restrict__ img,
    const float* __restrict__ flow,
    const float* __restrict__ metric,
    float* __restrict__ out,
    const int* __restrict__ counter,
    const float4* __restrict__ rec_vals,
    const int* __restrict__ rec_cells,
    int cap)
{
    __shared__ float acc[4][TH][LSTRIDE];   // 4*64*65*4 = 65 KB -> 2 blocks/CU

    const int tid = threadIdx.x;
    const int tx0 = blockIdx.x * TW;
    const int ty0 = blockIdx.y * TH;
    const int b   = blockIdx.z;

    // zero the accumulator
    float* const a = &acc[0][0][0];
    for (int i = tid; i < 4 * TH * LSTRIDE; i += NT) a[i] = 0.0f;
    __syncthreads();

    const float* const flowx = flow + (size_t)(b * 2 + 0) * HW_;
    const float* const flowy = flow + (size_t)(b * 2 + 1) * HW_;
    const float* const metr  = metric + (size_t)b * HW_;
    const float* const img0  = img + (size_t)(b * 3 + 0) * HW_;
    const float* const img1  = img + (size_t)(b * 3 + 1) * HW_;
    const float* const img2  = img + (size_t)(b * 3 + 2) * HW_;

    // scan the source window
    for (int i = tid; i < WX * WY; i += NT) {
        const int wy = i / WX;
        const int wx = i - wy * WX;
        const int sx = tx0 - R + wx;
        const int sy = ty0 - R + wy;
        if (sx < 0 || sx >= W_ || sy < 0 || sy >= H_) continue;
        const int p = (sy << 10) + sx;

        const float fx = flowx[p] + (float)sx;
        const float fy = flowy[p] + (float)sy;
        const float x0f = floorf(fx);
        const float y0f = floorf(fy);
        const int x0 = (int)x0f;
        const int y0 = (int)y0f;

        // dest-reject before touching metric/img: any corner in this tile?
        if (x0 + 1 < tx0 || x0 > tx0 + TW - 1 ||
            y0 + 1 < ty0 || y0 > ty0 + TH - 1) continue;

        const float wgt = __expf(metr[p]);
        const float v0 = img0[p] * wgt;
        const float v1 = img1[p] * wgt;
        const float v2 = img2[p] * wgt;
        const float wx1 = fx - x0f, wx0f_ = 1.0f - wx1;
        const float wy1 = fy - y0f, wy0f_ = 1.0f - wy1;

#pragma unroll
        for (int dy = 0; dy < 2; ++dy) {
            const int yi = y0 + dy;
            const int ly = yi - ty0;
            if ((unsigned)ly >= TH) continue;
#pragma unroll
            for (int dx = 0; dx < 2; ++dx) {
                const int xi = x0 + dx;
                const int lx = xi - tx0;
                if ((unsigned)lx >= TW) continue;
                // exact-partition predicate (complement handled by outliers)
                if (abs(xi - sx) > R || abs(yi - sy) > R) continue;
                const float w = (dx ? wx1 : wx0f_) * (dy ? wy1 : wy0f_);
                atomicAdd(&acc[0][ly][lx], v0 * w);
                atomicAdd(&acc[1][ly][lx], v1 * w);
                atomicAdd(&acc[2][ly][lx], v2 * w);
                atomicAdd(&acc[3][ly][lx], wgt * w);
            }
        }
    }
    __syncthreads();

    // fold in outlier records (n is ~0 in practice)
    const int n = min(*counter, cap);
    for (int r = tid; r < n; r += NT) {
        const int cell = rec_cells[r];
        const int rb = cell >> 20;
        if (rb != b) continue;
        const int q  = cell & (HW_ - 1);
        const int yi = q >> 10;
        const int xi = q & (W_ - 1);
        const int ly = yi - ty0;
        const int lx = xi - tx0;
        if ((unsigned)ly >= TH || (unsigned)lx >= TW) continue;
        const float4 v = rec_vals[r];
        atomicAdd(&acc[0][ly][lx], v.x);
        atomicAdd(&acc[1][ly][lx], v.y);
        atomicAdd(&acc[2][ly][lx], v.z);
        atomicAdd(&acc[3][ly][lx], v.w);
    }
    __syncthreads();

    // normalize + store (coalesced scalar stores per plane)
    for (int i = tid; i < TH * TW; i += NT) {
        const int ly = i >> 6;          // / TW
        const int lx = i & (TW - 1);
        const float wsum = acc[3][ly][lx];
        const float inv = (wsum == 0.0f) ? 1.0f : 1.0f / wsum;
        const int q = ((ty0 + ly) << 10) + (tx0 + lx);
        out[(size_t)(b * 3 + 0) * HW_ + q] = acc[0][ly][lx] * inv;
        out[(size_t)(b * 3 + 1) * HW_ + q] = acc[1][ly][lx] * inv;
        out[(size_t)(b * 3 + 2) * HW_ + q] = acc[2][ly][lx] * inv;
    }
}

extern "C" void kernel_launch(void* const* d_in, const int* in_sizes, int n_in,
                              void* d_out, int out_size, void* d_ws, size_t ws_size,
                              hipStream_t stream)
{
    const float* img    = (const float*)d_in[0];
    const float* flow   = (const float*)d_in[1];
    const float* metric = (const float*)d_in[2];
    float* out = (float*)d_out;

    // ws layout: [0..63] counter/header, then float4 vals[cap], then int cells[cap]
    int* counter = (int*)d_ws;
    long long avail = (long long)ws_size - 64;
    int cap = (int)min((long long)(1 << 22), avail > 0 ? avail / 20 : 0);
    float4* rec_vals = (float4*)((char*)d_ws + 64);
    int* rec_cells = (int*)((char*)d_ws + 64 + (size_t)cap * sizeof(float4));

    hipMemsetAsync(counter, 0, 64, stream);

    {
        const int n = B_ * HW_;
        outlier_kernel<<<(n + 255) / 256, 256, 0, stream>>>(
            img, flow, metric, counter, rec_vals, rec_cells, cap);
    }
    {
        dim3 grid(W_ / TW, H_ / TH, B_);   // 16 x 16 x 8
        splat_tile_kernel<<<grid, NT, 0, stream>>>(
            img, flow, metric, out, counter, rec_vals, rec_cells, cap);
    }
}